// Round 1
// baseline (122.421 us; speedup 1.0000x reference)
//
#include <hip/hip_runtime.h>
#include <hip/hip_bf16.h>
#include <stdint.h>

#define NPIX 512
#define NBC  96
#define BM 128
#define BN 128
#define BK 32
#define NKT (NPIX / BK)   // 16

typedef __attribute__((ext_vector_type(8))) short bf16x8;
typedef __attribute__((ext_vector_type(4))) float f32x4;

__device__ __forceinline__ unsigned short f2bf(float f) {
    __hip_bfloat16 h = __float2bfloat16(f);
    union { __hip_bfloat16 h; unsigned short u; } v;
    v.h = h;
    return v.u;
}

#define GLD16(g, l) __builtin_amdgcn_global_load_lds( \
    (const __attribute__((address_space(1))) void*)(const void*)(g), \
    (__attribute__((address_space(3))) void*)(void*)(l), 16, 0, 0)

// ---------------- D basis: D[k][n] = bf16(2*cos(pi*(2n+1)*k/1024)) ----------------
__global__ void k_basis(unsigned short* __restrict__ D) {
    int idx = blockIdx.x * 256 + threadIdx.x;      // 0 .. 262143
    int k = idx >> 9, n = idx & 511;
    int m = ((2 * n + 1) * k) & 2047;              // mod 4N: cos period, keeps arg small
    float ang = (float)m * 3.06796157577128218e-03f;  // pi/1024
    D[idx] = f2bf(2.0f * cosf(ang));
}

// ---------------- Stage 1: sT[l][h] = bf16( (X @ D^T)[h][l] ) ----------------
__global__ __launch_bounds__(256) void k_stage1(
        const float* __restrict__ X,
        const unsigned short* __restrict__ D,
        unsigned short* __restrict__ sT) {
    __shared__ float          As[2][BM * BK];          // fp32 X tile, 2 x 16KB
    __shared__ unsigned short Bs[2][BN * BK];          // bf16 D tile, 2 x 8KB

    const int bc = blockIdx.z;
    const int h0 = blockIdx.y * BM;
    const int l0 = blockIdx.x * BN;
    const float* Xbc = X + (size_t)bc * NPIX * NPIX;
    unsigned short* sTbc = sT + (size_t)bc * NPIX * NPIX;

    const int tid  = threadIdx.x;
    const int lane = tid & 63;
    const int wid  = tid >> 6;
    const int wr = wid >> 1, wc = wid & 1;             // 2x2 wave grid, 64x64 each
    const int rm = lane & 15;                          // fragment row index
    const int kq = lane >> 4;                          // K quadrant (0..3)

    f32x4 acc[4][4] = {};

    auto stage = [&](int kt, int buf) {
        // A tile: 128 rows x 32 fp32 = 1024 chunks of 16B; XOR-swizzled source
        #pragma unroll
        for (int it = 0; it < 4; ++it) {
            int chunk = it * 256 + tid;
            int r = chunk >> 3, c = chunk & 7;
            int cs = c ^ (r & 7);
            GLD16(Xbc + (size_t)(h0 + r) * NPIX + kt * BK + cs * 4,
                  &As[buf][chunk * 4]);
        }
        // B tile: 128 rows x 32 bf16 = 512 chunks of 16B
        #pragma unroll
        for (int it = 0; it < 2; ++it) {
            int chunk = it * 256 + tid;
            int r = chunk >> 2, c = chunk & 3;
            int cs = c ^ (r & 3) ^ ((r >> 2) & 3);
            GLD16(D + (size_t)(l0 + r) * NPIX + kt * BK + cs * 8,
                  &Bs[buf][chunk * 8]);
        }
    };

    stage(0, 0);
    int cur = 0;
    for (int kt = 0; kt < NKT; ++kt) {
        __syncthreads();                                // tile kt ready; prev reads done
        if (kt + 1 < NKT) stage(kt + 1, cur ^ 1);       // async prefetch next tile

        bf16x8 af[4], bfr[4];
        #pragma unroll
        for (int m = 0; m < 4; ++m) {
            int row = wr * 64 + m * 16 + rm;
            int c0 = kq * 2;
            int p0 = c0 ^ (row & 7);
            int p1 = (c0 + 1) ^ (row & 7);
            f32x4 v0 = *(const f32x4*)&As[cur][row * BK + p0 * 4];
            f32x4 v1 = *(const f32x4*)&As[cur][row * BK + p1 * 4];
            bf16x8 a;
            #pragma unroll
            for (int j = 0; j < 4; ++j) a[j]     = (short)f2bf(v0[j]);
            #pragma unroll
            for (int j = 0; j < 4; ++j) a[4 + j] = (short)f2bf(v1[j]);
            af[m] = a;
        }
        #pragma unroll
        for (int n = 0; n < 4; ++n) {
            int row = wc * 64 + n * 16 + rm;
            int c = kq ^ (row & 3) ^ ((row >> 2) & 3);
            bfr[n] = *(const bf16x8*)&Bs[cur][row * BK + c * 8];
        }
        #pragma unroll
        for (int m = 0; m < 4; ++m)
            #pragma unroll
            for (int n = 0; n < 4; ++n)
                acc[m][n] = __builtin_amdgcn_mfma_f32_16x16x32_bf16(
                    af[m], bfr[n], acc[m][n], 0, 0, 0);
        cur ^= 1;
    }

    // Transposed epilogue: sT[l][h], lane holds 4 contiguous h per fragment
    #pragma unroll
    for (int m = 0; m < 4; ++m) {
        int h = h0 + wr * 64 + m * 16 + kq * 4;
        #pragma unroll
        for (int n = 0; n < 4; ++n) {
            int l = l0 + wc * 64 + n * 16 + rm;
            ushort4 w;
            w.x = f2bf(acc[m][n][0]);
            w.y = f2bf(acc[m][n][1]);
            w.z = f2bf(acc[m][n][2]);
            w.w = f2bf(acc[m][n][3]);
            *(ushort4*)&sTbc[(size_t)l * NPIX + h] = w;
        }
    }
}

// ---------------- Stage 2: out[k][l] = (sum_h D[k][h]*sT[l][h]) * 1e-3 ----------------
__global__ __launch_bounds__(256) void k_stage2(
        const unsigned short* __restrict__ D,
        const unsigned short* __restrict__ sT,
        float* __restrict__ out) {
    __shared__ unsigned short As[2][BM * BK];          // bf16 D tile
    __shared__ unsigned short Bs[2][BN * BK];          // bf16 sT tile

    const int bc = blockIdx.z;
    const int k0 = blockIdx.y * BM;
    const int l0 = blockIdx.x * BN;
    const unsigned short* sTbc = sT + (size_t)bc * NPIX * NPIX;
    float* obc = out + (size_t)bc * NPIX * NPIX;

    const int tid  = threadIdx.x;
    const int lane = tid & 63;
    const int wid  = tid >> 6;
    const int wr = wid >> 1, wc = wid & 1;
    const int rm = lane & 15;
    const int kq = lane >> 4;

    f32x4 acc[4][4] = {};

    auto stage = [&](int kt, int buf) {
        #pragma unroll
        for (int it = 0; it < 2; ++it) {
            int chunk = it * 256 + tid;
            int r = chunk >> 2, c = chunk & 3;
            int cs = c ^ (r & 3) ^ ((r >> 2) & 3);
            GLD16(D + (size_t)(k0 + r) * NPIX + kt * BK + cs * 8,
                  &As[buf][chunk * 8]);
        }
        #pragma unroll
        for (int it = 0; it < 2; ++it) {
            int chunk = it * 256 + tid;
            int r = chunk >> 2, c = chunk & 3;
            int cs = c ^ (r & 3) ^ ((r >> 2) & 3);
            GLD16(sTbc + (size_t)(l0 + r) * NPIX + kt * BK + cs * 8,
                  &Bs[buf][chunk * 8]);
        }
    };

    stage(0, 0);
    int cur = 0;
    for (int kt = 0; kt < NKT; ++kt) {
        __syncthreads();
        if (kt + 1 < NKT) stage(kt + 1, cur ^ 1);

        bf16x8 af[4], bfr[4];
        #pragma unroll
        for (int m = 0; m < 4; ++m) {
            int row = wr * 64 + m * 16 + rm;
            int c = kq ^ (row & 3) ^ ((row >> 2) & 3);
            af[m] = *(const bf16x8*)&As[cur][row * BK + c * 8];
        }
        #pragma unroll
        for (int n = 0; n < 4; ++n) {
            int row = wc * 64 + n * 16 + rm;
            int c = kq ^ (row & 3) ^ ((row >> 2) & 3);
            bfr[n] = *(const bf16x8*)&Bs[cur][row * BK + c * 8];
        }
        #pragma unroll
        for (int m = 0; m < 4; ++m)
            #pragma unroll
            for (int n = 0; n < 4; ++n)
                acc[m][n] = __builtin_amdgcn_mfma_f32_16x16x32_bf16(
                    af[m], bfr[n], acc[m][n], 0, 0, 0);
        cur ^= 1;
    }

    #pragma unroll
    for (int m = 0; m < 4; ++m) {
        int k_ = k0 + wr * 64 + m * 16 + kq * 4;
        #pragma unroll
        for (int n = 0; n < 4; ++n) {
            int l_ = l0 + wc * 64 + n * 16 + rm;
            #pragma unroll
            for (int r = 0; r < 4; ++r)
                obc[(size_t)(k_ + r) * NPIX + l_] = acc[m][n][r] * 1.0e-3f;
        }
    }
}

extern "C" void kernel_launch(void* const* d_in, const int* in_sizes, int n_in,
                              void* d_out, int out_size, void* d_ws, size_t ws_size,
                              hipStream_t stream) {
    const float* img = (const float*)d_in[0];
    float* out = (float*)d_out;

    unsigned short* D  = (unsigned short*)d_ws;                       // 512 KB
    unsigned short* sT = (unsigned short*)((char*)d_ws + 512 * 1024); // 48 MB

    k_basis<<<dim3(512 * 512 / 256), dim3(256), 0, stream>>>(D);

    dim3 grid(NPIX / BN, NPIX / BM, NBC);
    k_stage1<<<grid, dim3(256), 0, stream>>>(img, D, sT);
    k_stage2<<<grid, dim3(256), 0, stream>>>(D, sT, out);
}

// Round 2
// 101.178 us; speedup vs baseline: 1.2100x; 1.2100x over previous
//
#include <hip/hip_runtime.h>
#include <hip/hip_bf16.h>
#include <stdint.h>

#define NPIX 512
#define NBC  96
#define BM 128
#define BN 128
#define BK 32
#define NKT (NPIX / BK)   // 16
#define NWG1 (4 * 4 * NBC) // 1536 blocks for stage1

typedef __attribute__((ext_vector_type(8))) short bf16x8;
typedef __attribute__((ext_vector_type(4))) float f32x4;

__device__ __forceinline__ unsigned short f2bf(float f) {
    __hip_bfloat16 h = __float2bfloat16(f);
    union { __hip_bfloat16 h; unsigned short u; } v;
    v.h = h;
    return v.u;
}

#define GLD16(g, l) __builtin_amdgcn_global_load_lds( \
    (const __attribute__((address_space(1))) void*)(const void*)(g), \
    (__attribute__((address_space(3))) void*)(void*)(l), 16, 0, 0)

// ---------------- D basis: D[k][n] = bf16(2*cos(pi*(2n+1)*k/1024)) ----------------
__global__ void k_basis(unsigned short* __restrict__ D) {
    int idx = blockIdx.x * 256 + threadIdx.x;      // 0 .. 262143
    int k = idx >> 9, n = idx & 511;
    int m = ((2 * n + 1) * k) & 2047;              // mod 4N: cos period, keeps arg small
    float ang = (float)m * 3.06796157577128218e-03f;  // pi/1024
    D[idx] = f2bf(2.0f * cosf(ang));
}

// ---------------- Stage 1: sT[l][h] = bf16( (X @ D^T)[h][l] ) ----------------
// A (X) reg-staged fp32->bf16 into LDS; B (D) via global_load_lds.
__global__ __launch_bounds__(256) void k_stage1(
        const float* __restrict__ X,
        const unsigned short* __restrict__ D,
        unsigned short* __restrict__ sT) {
    __shared__ unsigned short As[2][BM * BK];          // bf16 X tile, 2 x 8KB
    __shared__ unsigned short Bs[2][BN * BK];          // bf16 D tile, 2 x 8KB

    // Bijective XCD-chunked swizzle: 1536 = 8 XCDs x 192 consecutive blocks.
    const int bid = blockIdx.x;
    const int nb  = (bid & 7) * (NWG1 / 8) + (bid >> 3);
    const int bx = nb & 3, by = (nb >> 2) & 3, bc = nb >> 4;
    const int h0 = by * BM;
    const int l0 = bx * BN;
    const float* Xbc = X + (size_t)bc * NPIX * NPIX;
    unsigned short* sTbc = sT + (size_t)bc * NPIX * NPIX;

    const int tid  = threadIdx.x;
    const int lane = tid & 63;
    const int wid  = tid >> 6;
    const int wr = wid >> 1, wc = wid & 1;             // 2x2 wave grid, 64x64 each
    const int rm = lane & 15;                          // fragment row index
    const int kq = lane >> 4;                          // K quadrant (0..3)

    f32x4 acc[4][4] = {};
    float4 av[4];                                      // in-flight A (issue early, write late)

    auto loadA = [&](int kt) {
        #pragma unroll
        for (int it = 0; it < 4; ++it) {
            int chunk = it * 256 + tid;
            int r = chunk >> 3, c = chunk & 7;
            av[it] = *(const float4*)(Xbc + (size_t)(h0 + r) * NPIX + kt * BK + c * 4);
        }
    };
    auto writeA = [&](int buf) {
        #pragma unroll
        for (int it = 0; it < 4; ++it) {
            int chunk = it * 256 + tid;
            int r = chunk >> 3, c = chunk & 7;
            int g = c >> 1;
            int gs = g ^ (r & 3) ^ ((r >> 2) & 3);     // 16B-granule XOR swizzle
            ushort4 w;
            w.x = f2bf(av[it].x); w.y = f2bf(av[it].y);
            w.z = f2bf(av[it].z); w.w = f2bf(av[it].w);
            *(ushort4*)&As[buf][r * 32 + gs * 8 + (c & 1) * 4] = w;
        }
    };
    auto stageB = [&](int kt, int buf) {
        #pragma unroll
        for (int it = 0; it < 2; ++it) {
            int chunk = it * 256 + tid;
            int r = chunk >> 2, c = chunk & 3;
            int cs = c ^ (r & 3) ^ ((r >> 2) & 3);     // pre-swizzled source, linear dest
            GLD16(D + (size_t)(l0 + r) * NPIX + kt * BK + cs * 8,
                  &Bs[buf][chunk * 8]);
        }
    };

    loadA(0);
    stageB(0, 0);
    writeA(0);
    __syncthreads();

    int cur = 0;
    for (int kt = 0; kt < NKT; ++kt) {
        if (kt + 1 < NKT) { loadA(kt + 1); stageB(kt + 1, cur ^ 1); }

        bf16x8 af[4], bfr[4];
        #pragma unroll
        for (int m = 0; m < 4; ++m) {
            int row = wr * 64 + m * 16 + rm;
            int gs = kq ^ (row & 3) ^ ((row >> 2) & 3);
            af[m] = *(const bf16x8*)&As[cur][row * BK + gs * 8];
        }
        #pragma unroll
        for (int n = 0; n < 4; ++n) {
            int row = wc * 64 + n * 16 + rm;
            int cs = kq ^ (row & 3) ^ ((row >> 2) & 3);
            bfr[n] = *(const bf16x8*)&Bs[cur][row * BK + cs * 8];
        }
        #pragma unroll
        for (int m = 0; m < 4; ++m)
            #pragma unroll
            for (int n = 0; n < 4; ++n)
                acc[m][n] = __builtin_amdgcn_mfma_f32_16x16x32_bf16(
                    af[m], bfr[n], acc[m][n], 0, 0, 0);

        if (kt + 1 < NKT) writeA(cur ^ 1);             // regs -> bf16 LDS (next buffer)
        __syncthreads();
        cur ^= 1;
    }

    // Transposed epilogue: sT[l][h], lane holds 4 contiguous h per fragment
    #pragma unroll
    for (int m = 0; m < 4; ++m) {
        int h = h0 + wr * 64 + m * 16 + kq * 4;
        #pragma unroll
        for (int n = 0; n < 4; ++n) {
            int l = l0 + wc * 64 + n * 16 + rm;
            ushort4 w;
            w.x = f2bf(acc[m][n][0]);
            w.y = f2bf(acc[m][n][1]);
            w.z = f2bf(acc[m][n][2]);
            w.w = f2bf(acc[m][n][3]);
            *(ushort4*)&sTbc[(size_t)l * NPIX + h] = w;
        }
    }
}

// ---------------- Stage 2: out[k][l] = (sum_h D[k][h]*sT[l][h]) * 1e-3 ----------------
__global__ __launch_bounds__(256) void k_stage2(
        const unsigned short* __restrict__ D,
        const unsigned short* __restrict__ sT,
        float* __restrict__ out) {
    __shared__ unsigned short As[2][BM * BK];          // bf16 D tile
    __shared__ unsigned short Bs[2][BN * BK];          // bf16 sT tile

    const int bc = blockIdx.z;
    const int k0 = blockIdx.y * BM;
    const int l0 = blockIdx.x * BN;
    const unsigned short* sTbc = sT + (size_t)bc * NPIX * NPIX;
    float* obc = out + (size_t)bc * NPIX * NPIX;

    const int tid  = threadIdx.x;
    const int lane = tid & 63;
    const int wid  = tid >> 6;
    const int wr = wid >> 1, wc = wid & 1;
    const int rm = lane & 15;
    const int kq = lane >> 4;

    f32x4 acc[4][4] = {};

    auto stage = [&](int kt, int buf) {
        #pragma unroll
        for (int it = 0; it < 2; ++it) {
            int chunk = it * 256 + tid;
            int r = chunk >> 2, c = chunk & 3;
            int cs = c ^ (r & 3) ^ ((r >> 2) & 3);
            GLD16(D + (size_t)(k0 + r) * NPIX + kt * BK + cs * 8,
                  &As[buf][chunk * 8]);
        }
        #pragma unroll
        for (int it = 0; it < 2; ++it) {
            int chunk = it * 256 + tid;
            int r = chunk >> 2, c = chunk & 3;
            int cs = c ^ (r & 3) ^ ((r >> 2) & 3);
            GLD16(sTbc + (size_t)(l0 + r) * NPIX + kt * BK + cs * 8,
                  &Bs[buf][chunk * 8]);
        }
    };

    stage(0, 0);
    int cur = 0;
    for (int kt = 0; kt < NKT; ++kt) {
        __syncthreads();
        if (kt + 1 < NKT) stage(kt + 1, cur ^ 1);

        bf16x8 af[4], bfr[4];
        #pragma unroll
        for (int m = 0; m < 4; ++m) {
            int row = wr * 64 + m * 16 + rm;
            int c = kq ^ (row & 3) ^ ((row >> 2) & 3);
            af[m] = *(const bf16x8*)&As[cur][row * BK + c * 8];
        }
        #pragma unroll
        for (int n = 0; n < 4; ++n) {
            int row = wc * 64 + n * 16 + rm;
            int c = kq ^ (row & 3) ^ ((row >> 2) & 3);
            bfr[n] = *(const bf16x8*)&Bs[cur][row * BK + c * 8];
        }
        #pragma unroll
        for (int m = 0; m < 4; ++m)
            #pragma unroll
            for (int n = 0; n < 4; ++n)
                acc[m][n] = __builtin_amdgcn_mfma_f32_16x16x32_bf16(
                    af[m], bfr[n], acc[m][n], 0, 0, 0);
        cur ^= 1;
    }

    #pragma unroll
    for (int m = 0; m < 4; ++m) {
        int k_ = k0 + wr * 64 + m * 16 + kq * 4;
        #pragma unroll
        for (int n = 0; n < 4; ++n) {
            int l_ = l0 + wc * 64 + n * 16 + rm;
            #pragma unroll
            for (int r = 0; r < 4; ++r)
                obc[(size_t)(k_ + r) * NPIX + l_] = acc[m][n][r] * 1.0e-3f;
        }
    }
}

extern "C" void kernel_launch(void* const* d_in, const int* in_sizes, int n_in,
                              void* d_out, int out_size, void* d_ws, size_t ws_size,
                              hipStream_t stream) {
    const float* img = (const float*)d_in[0];
    float* out = (float*)d_out;

    unsigned short* D  = (unsigned short*)d_ws;                       // 512 KB
    unsigned short* sT = (unsigned short*)((char*)d_ws + 512 * 1024); // 48 MB

    k_basis<<<dim3(512 * 512 / 256), dim3(256), 0, stream>>>(D);

    k_stage1<<<dim3(NWG1), dim3(256), 0, stream>>>(img, D, sT);

    dim3 grid2(NPIX / BN, NPIX / BM, NBC);
    k_stage2<<<grid2, dim3(256), 0, stream>>>(D, sT, out);
}